// Round 12
// baseline (657.670 us; speedup 1.0000x reference)
//
#include <hip/hip_runtime.h>
#include <hip/hip_bf16.h>

#define LF 64
#define NBAGS 5
#define BROWS 2048
#define OUTC 320
#define KC 2048
#define NMT 16
#define NCHUNKS 90                 // bags 1..4: 30 + 1 + 49 + 10
#define NPAIRS 90                  // 180 padded 1024-k windows, 2 per wave

#define WS_HEAD 65536
#define NTILES 2912                // 32 tiles per padded chunk, bags 0..4
#define WP_BYTES ((size_t)NTILES * 8192)
#define BM_OFF (WS_HEAD + WP_BYTES)
#define BM_BYTES ((size_t)BROWS * 23040)            // 47,185,920
#define PART_OFF (BM_OFF + BM_BYTES)
#define PART_BYTES ((size_t)NCHUNKS * BROWS * LF * 4)

typedef __attribute__((ext_vector_type(8))) short short8;
typedef __attribute__((ext_vector_type(4))) float f32x4;
typedef unsigned long long u64;

struct BagArgs {
    const int*   A[NBAGS];
    const float* W[NBAGS];
    int K[NBAGS];
    int cstart[NBAGS + 1];   // KC-chunk prefix, bags 1..4
    int tstart[NBAGS + 1];   // 64-k tile prefix (32 per padded chunk)
    long long bmoff[NBAGS];  // bitmask byte offset per bag
    int rsp[NBAGS];          // padded bitmask row stride, bytes (nch*256)
};

__device__ __forceinline__ unsigned short f2bf(float f) {
    unsigned u = __float_as_uint(f);
    u += 0x7FFFu + ((u >> 16) & 1u);   // round-to-nearest-even
    return (unsigned short)(u >> 16);
}

// Pack W (f32 [K][64]) -> bf16 tiles of 64 k (8 KB), permuted so the B
// fragment matches A frags where lane (fr,kg), frag m holds k=kg*16+m*8+[0,8).
// k -> block = ((k>>3)&1)*4 + (k>>4);  short idx = (block*64 + c)*8 + (k&7).
// Zero-filled past K (incl. whole pad tiles).  [validated R5-R11]
__global__ __launch_bounds__(256) void pack_w(BagArgs args,
                                              unsigned short* __restrict__ Wp) {
    __shared__ unsigned short ls[4][4096];
    const int wv = threadIdx.x >> 6;
    const int c  = threadIdx.x & 63;
    const int gtile = blockIdx.x * 4 + wv;

    int bag = 0;
#pragma unroll
    for (int b = 1; b < NBAGS; ++b)
        if (gtile >= args.tstart[b]) bag = b;
    const int lt = gtile - args.tstart[bag];
    const float* __restrict__ W = args.W[bag];
    const int K = args.K[bag];

    unsigned short* L = ls[wv];
#pragma unroll 8
    for (int k = 0; k < 64; ++k) {
        const int gk = lt * 64 + k;
        float v = (gk < K) ? W[(size_t)gk * LF + c] : 0.f;
        const int block = ((k >> 3) & 1) * 4 + (k >> 4);
        L[(block * LF + c) * 8 + (k & 7)] = f2bf(v);
    }
    __syncthreads();
    unsigned short* dst = Wp + ((size_t)gtile << 12);
#pragma unroll
    for (int j = 0; j < 8; ++j)
        *(short8*)(dst + c * 8 + j * 512) = *(const short8*)(L + c * 8 + j * 512);
}

// Pass 1: fill-shaped ballot compress. Wave = TWO 1024-k windows of one row:
// 32 independent coalesced dword loads (8 KB in flight), 32 __ballot packs
// (bit L == lane L == flat k order [validated R10]), two coalesced 128 B
// stores. Rows padded with zero bits to 256 B per 2048-k chunk.
__global__ __launch_bounds__(256) void compress(BagArgs args,
                                                unsigned char* __restrict__ bm) {
    const int lane = threadIdx.x & 63;
    const int pair = blockIdx.x * 4 + (threadIdx.x >> 6);
    if (pair >= NPAIRS) return;
    const int w0 = pair * 2;          // window ids; bag boundaries 60/62/160 all even
    int bag, base;
    if      (w0 >= 160) { bag = 4; base = 160; }
    else if (w0 >=  62) { bag = 3; base = 62;  }
    else if (w0 >=  60) { bag = 2; base = 60;  }
    else                { bag = 1; base = 0;   }
    const int row = blockIdx.y;
    const int K   = args.K[bag];
    const int* __restrict__ A = args.A[bag] + (size_t)row * K;
    const int cb = (w0 - base) * 1024;
    unsigned char* __restrict__ dst =
        bm + args.bmoff[bag] + (size_t)row * args.rsp[bag] + (w0 - base) * 128;

    int v0[16], v1[16];
#pragma unroll
    for (int j = 0; j < 16; ++j) {
        const int c0 = cb + j * 64 + lane;
        v0[j] = (c0 < K) ? A[c0] : 0;
    }
#pragma unroll
    for (int j = 0; j < 16; ++j) {
        const int c1 = cb + 1024 + j * 64 + lane;
        v1[j] = (c1 < K) ? A[c1] : 0;
    }
    u64 sel0 = 0, sel1 = 0;
#pragma unroll
    for (int j = 0; j < 16; ++j) {
        const u64 b = __ballot(v0[j] != 0);
        sel0 = (lane == j) ? b : sel0;     // static unroll: stays in regs
    }
#pragma unroll
    for (int j = 0; j < 16; ++j) {
        const u64 b = __ballot(v1[j] != 0);
        sel1 = (lane == j) ? b : sel1;
    }
    if (lane < 16) {
        *(u64*)(dst + lane * 8)       = sel0;
        *(u64*)(dst + 128 + lane * 8) = sel1;
    }
}

// Pass 2: MFMA GEMM off the padded bitmask (R11 structure, + XCD swizzle so
// all 16 m-tiles of a chunk share one XCD's L2 for the Wp re-reads).
__global__ __launch_bounds__(256) void bag_gemm(BagArgs args,
                                                const unsigned short* __restrict__ Wp,
                                                const unsigned char* __restrict__ bm,
                                                float* __restrict__ part,
                                                float* __restrict__ sums)
{
    __shared__ unsigned bits[128 * 64];   // [row][word], quad-swizzled: 32 KB

    const int tid  = threadIdx.x;
    const int wave = tid >> 6;
    const int lane = tid & 63;
    const int fr   = lane & 15;
    const int kg   = lane >> 4;

    // bijective XCD swizzle: 1440 blocks = 8 XCDs x 180   [guide T1]
    const int bsw = (blockIdx.x & 7) * (NCHUNKS * NMT / 8) + (blockIdx.x >> 3);
    const int g  = bsw >> 4;           // global chunk (bags 1..4)
    const int mt = bsw & 15;           // m-tile (128 rows)

    int bag = 1;
#pragma unroll
    for (int b = 2; b < NBAGS; ++b)
        if (g >= args.cstart[b]) bag = b;
    const int chunk = g - args.cstart[bag];
    const int row0b = mt * 128;

    // ---- stage: wave reads 32 rows x 256 B, 8 instrs of 1 KB coalesced ----
    {
        const unsigned char* srcb = bm + args.bmoff[bag] + chunk * 256
                                  + (size_t)row0b * args.rsp[bag];
#pragma unroll
        for (int it = 0; it < 8; ++it) {
            const int lrow = wave * 32 + it * 4 + (lane >> 4);
            const uint4 v = *(const uint4*)(srcb + (size_t)lrow * args.rsp[bag]
                                            + (lane & 15) * 16);
            const int sq = (lane & 15) ^ (lrow & 15);
            *(uint4*)&bits[lrow * 64 + sq * 4] = v;
        }
    }
    __syncthreads();

    // ---- compute ----------------------------------------------------------
    const unsigned short* __restrict__ pB =
        Wp + ((size_t)(args.tstart[bag] + chunk * 32) << 12) + (kg * LF + fr) * 8;

    f32x4 acc0[4], acc1[4];
#pragma unroll
    for (int i = 0; i < 4; ++i) {
        acc0[i] = (f32x4){0.f, 0.f, 0.f, 0.f};
        acc1[i] = (f32x4){0.f, 0.f, 0.f, 0.f};
    }
    f32x4 accS0 = (f32x4){0.f, 0.f, 0.f, 0.f};
    f32x4 accS1 = (f32x4){0.f, 0.f, 0.f, 0.f};
    const int4 uo = make_int4(0x3F803F80, 0x3F803F80, 0x3F803F80, 0x3F803F80);
    const short8 ones = *(const short8*)&uo;

    auto loadB = [&](int ss, short8 (&y)[2][4]) {
        const unsigned short* p = pB + (size_t)ss * 4096;
#pragma unroll
        for (int m = 0; m < 2; ++m)
#pragma unroll
            for (int ni = 0; ni < 4; ++ni)
                y[m][ni] = *(const short8*)(p + m * 2048 + ni * 128);
    };
    // 2 bits -> dword of 2 bf16 (0x3F80 = bf16(1))   [validated R7-R11]
    auto bf16pair = [](unsigned b) -> int {
        return (int)((b & 1u) * 0x3F80u + (b & 2u) * 0x1FC00000u);
    };
    auto mkfrag = [&](unsigned byte) -> short8 {
        int4 u = make_int4(bf16pair(byte), bf16pair(byte >> 2),
                           bf16pair(byte >> 4), bf16pair(byte >> 6));
        return *(short8*)&u;
    };
    auto compute = [&](int ss, const short8 (&y)[2][4]) {
        const int wi = ss * 2 + (kg >> 1);
        const int wq = ((wi >> 2) ^ fr) * 4 + (wi & 3);
        const unsigned wrd0 = bits[(wave * 32 + fr) * 64 + wq];
        const unsigned wrd1 = bits[(wave * 32 + 16 + fr) * 64 + wq];
#pragma unroll
        for (int m = 0; m < 2; ++m) {
            const int sh = (kg & 1) * 16 + m * 8;      // [validated R9-R11]
            const short8 fa0 = mkfrag((wrd0 >> sh) & 0xFFu);
            const short8 fa1 = mkfrag((wrd1 >> sh) & 0xFFu);
            accS0 = __builtin_amdgcn_mfma_f32_16x16x32_bf16(fa0, ones, accS0, 0, 0, 0);
            accS1 = __builtin_amdgcn_mfma_f32_16x16x32_bf16(fa1, ones, accS1, 0, 0, 0);
#pragma unroll
            for (int ni = 0; ni < 4; ++ni) {
                acc0[ni] = __builtin_amdgcn_mfma_f32_16x16x32_bf16(fa0, y[m][ni], acc0[ni], 0, 0, 0);
                acc1[ni] = __builtin_amdgcn_mfma_f32_16x16x32_bf16(fa1, y[m][ni], acc1[ni], 0, 0, 0);
            }
        }
    };

    short8 Ba[2][4], Bb[2][4];
    loadB(0, Ba);
#pragma unroll 1
    for (int p = 0; p < 16; ++p) {
        loadB(2 * p + 1, Bb);
        __builtin_amdgcn_sched_barrier(0);
        compute(2 * p, Ba);
        loadB(min(2 * p + 2, 31), Ba);
        __builtin_amdgcn_sched_barrier(0);
        compute(2 * p + 1, Bb);
    }

    // popcounts from ones-MFMA (exact in f32)   [validated R9-R11]
    if (fr == 0) {
#pragma unroll
        for (int r = 0; r < 4; ++r) {
            atomicAdd(&sums[bag * BROWS + row0b + wave * 32 + kg * 4 + r],      accS0[r]);
            atomicAdd(&sums[bag * BROWS + row0b + wave * 32 + 16 + kg * 4 + r], accS1[r]);
        }
    }

    // C/D: col = lane&15 (=fr), row = kg*4 + reg   [validated R1-R11]
    float* dst = part + ((size_t)g * BROWS + row0b + wave * 32 + kg * 4) * LF + fr;
#pragma unroll
    for (int ni = 0; ni < 4; ++ni)
#pragma unroll
        for (int r = 0; r < 4; ++r) {
            dst[(size_t)(r) * LF + ni * 16]      = acc0[ni][r];
            dst[(size_t)(16 + r) * LF + ni * 16] = acc1[ni][r];
        }
}

// Sum split-K partials, normalize (incl. faithful "decades divided twice"
// bug), and compute the tiny K=12 decades bag directly in f32.
__global__ __launch_bounds__(256) void reduce_norm(BagArgs args,
                                                   const float* __restrict__ part,
                                                   float* __restrict__ out,
                                                   const float* __restrict__ sums)
{
    const int idx = blockIdx.x * 256 + threadIdx.x;
    if (idx >= BROWS * OUTC) return;
    const int row = idx / OUTC;
    const int c   = idx - row * OUTC;
    const int bag = c >> 6;
    const int col = c & 63;

    float v;
    if (bag == 0) {
        const int*   A0 = args.A[0];
        const float* W0 = args.W[0];
        float a = 0.f; int s = 0;
#pragma unroll
        for (int k = 0; k < 12; ++k) {
            const int x = A0[row * 12 + k];
            s += x;
            if (x) a += W0[k * LF + col];
        }
        if (s) a /= (float)s;
        const float sm = sums[1 * BROWS + row];   // ref bug: also divide by movie sum
        if (sm != 0.f) a /= sm;
        v = a;
    } else {
        float a = 0.f;
        for (int gg = args.cstart[bag]; gg < args.cstart[bag + 1]; ++gg)
            a += part[((size_t)gg * BROWS + row) * LF + col];
        v = a;
        if (bag >= 2) {
            const float s = sums[bag * BROWS + row];
            if (s != 0.f) v /= s;
        }
        // bag 1 (movies): never normalized (faithful to reference bug)
    }
    out[idx] = v;
}

// Correctness-only fallback (tiny ws): one thread per output element.
__global__ void naive_bag(BagArgs args, float* __restrict__ out) {
    const int row = blockIdx.x;
    const int c   = threadIdx.x;
    if (c >= OUTC) return;
    const int bag = c >> 6;
    const int col = c & 63;
    const int K = args.K[bag];
    const int* A = args.A[bag] + (size_t)row * K;
    const float* W = args.W[bag];
    float a = 0.f; int s = 0;
    for (int k = 0; k < K; ++k) {
        const int x = A[k];
        s += x;
        if (x) a += W[(size_t)k * LF + col];
    }
    if (bag != 1 && s) a /= (float)s;
    if (bag == 0) {
        const int* A1 = args.A[1] + (size_t)row * args.K[1];
        int sm = 0;
        for (int k = 0; k < args.K[1]; ++k) sm += A1[k];
        if (sm) a /= (float)sm;
    }
    out[(size_t)row * OUTC + c] = a;
}

extern "C" void kernel_launch(void* const* d_in, const int* in_sizes, int n_in,
                              void* d_out, int out_size, void* d_ws, size_t ws_size,
                              hipStream_t stream) {
    float* out = (float*)d_out;
    float* sums = (float*)d_ws;
    unsigned short* Wp = (unsigned short*)((char*)d_ws + WS_HEAD);
    unsigned char* bm  = (unsigned char*)((char*)d_ws + BM_OFF);
    float* part = (float*)((char*)d_ws + PART_OFF);

    BagArgs args;
    const int Ks[NBAGS] = {12, 60000, 32, 100000, 20000};
    int tcum = 0;
    for (int b = 0; b < NBAGS; ++b) {
        args.A[b] = (const int*)d_in[b];
        args.W[b] = (const float*)d_in[5 + b];
        args.K[b] = Ks[b];
        args.tstart[b] = tcum;
        tcum += ((Ks[b] + KC - 1) / KC) * 32;   // 32+960+32+1568+320 = 2912
    }
    args.tstart[NBAGS] = tcum;
    args.cstart[0] = 0;
    int ccum = 0;
    for (int b = 1; b < NBAGS; ++b) {
        args.cstart[b] = ccum;
        ccum += (Ks[b] + KC - 1) / KC;          // 30 + 1 + 49 + 10 = 90
    }
    args.cstart[NBAGS] = ccum;

    // padded bitmask: row stride = nch*256 B; zero bits fill pads
    args.rsp[0] = 0; args.bmoff[0] = 0;
    long long bcum = 0;
    for (int b = 1; b < NBAGS; ++b) {
        args.rsp[b] = ((Ks[b] + KC - 1) / KC) * 256;   // 7680,256,12544,2560
        args.bmoff[b] = bcum;
        bcum += (long long)BROWS * args.rsp[b];
    }

    const bool ok = ws_size >= PART_OFF + PART_BYTES;
    if (!ok) {
        naive_bag<<<BROWS, OUTC, 0, stream>>>(args, out);
        return;
    }

    hipMemsetAsync(sums, 0, NBAGS * BROWS * sizeof(float), stream);

    pack_w<<<tcum / 4, 256, 0, stream>>>(args, Wp);
    compress<<<dim3((NPAIRS + 3) / 4, BROWS), 256, 0, stream>>>(args, bm);
    bag_gemm<<<NCHUNKS * NMT, 256, 0, stream>>>(args, Wp, bm, part, sums);
    reduce_norm<<<(BROWS * OUTC + 255) / 256, 256, 0, stream>>>(args, part, out, sums);
}